// Round 4
// baseline (108.105 us; speedup 1.0000x reference)
//
#include <hip/hip_runtime.h>
#include <hip/hip_bf16.h>

// (B,T,E,H) = (4, 2048, 1024, 64); scale = E^-0.5 = 1/32.
// Ground truth: inputs fp32, output fp32. ws >= 268 MB.
// dur_us model: ~85.5 us fixed poison fills (2 x 42.7 us, immovable) +
// ~20 us controllable kernels/gaps (prep_w ~3, qkv ~10-13, attn ~5-7).
// R16: qkv W-staging via global_load_lds width=16 (removes VGPR round-trip +
// 12 ds_writes/thread/step — the m151/m193 staging-bound lever). Requires
// linear LDS dest (rule #21): pad-136 dropped for Ws; bank uniformity
// restored by XOR involution — source chunk ^= (row&7), read colb ^=
// (l16&7)<<4. Verified: 8 lanes per 4-bank group (uniform, same as pad-136).
// 2 blocks/CU co-residency preserved (52.25 KB LDS) — R14 proved it IS the
// pipeline (1 block/CU stalled at MfmaUtil 2.5%).
// attn_mfma6 unchanged (R15: balanced pairing + shfl-lS + setprio, -12.8 us).
constexpr int Bc = 4;
constexpr int Tc = 2048;
constexpr int Ec = 1024;
constexpr int Hc = 64;
constexpr float SCALE = 0.03125f;

typedef short  short8  __attribute__((ext_vector_type(8)));
typedef float  floatx4 __attribute__((ext_vector_type(4)));

__device__ __forceinline__ unsigned short f2bf(float f) {  // RNE
    union { float f; unsigned int i; } x;
    x.f = f;
    unsigned int r = x.i + 0x7fffu + ((x.i >> 16) & 1u);
    return (unsigned short)(r >> 16);
}

// ---------------------------------------------------------------------------
// Kernel 0: W fp32 [E][H] -> Wt bf16 [H][E], x3 (r7-r12-proven). ~3 us.
// ---------------------------------------------------------------------------
__global__ __launch_bounds__(256) void prep_w(
    const float* __restrict__ Wq, const float* __restrict__ Wk,
    const float* __restrict__ Wv, unsigned short* __restrict__ Wt)
{
    const float* W = blockIdx.y == 0 ? Wq : (blockIdx.y == 1 ? Wk : Wv);
    unsigned short* D = Wt + (size_t)blockIdx.y * (Ec * Hc);
    const int i0 = blockIdx.x * 1024 + threadIdx.x * 4;
    const float4 f = *(const float4*)(W + i0);
    const float v[4] = {f.x, f.y, f.z, f.w};
    #pragma unroll
    for (int j = 0; j < 4; ++j) {
        const int i = i0 + j;            // i = e*64 + h
        D[(i & 63) * Ec + (i >> 6)] = f2bf(v[j]);
    }
}

// ---------------------------------------------------------------------------
// Kernel 1: FUSED QKV projection, MFMA 16x16x32 bf16, K=128 staging depth.
// Grid 512 x 256 thr (2 blocks/CU — the co-residency is the pipeline).
// R16: W staged via global_load_lds dwordx4 into UNPADDED Ws[3][64][128].
//   Involution (both-sides): LDS byte (row, colb') holds W element at
//   colb = colb' ^ ((row&7)<<4).
//   - store side: lane writing linear chunk (flat&15) sources global chunk
//     (flat&15) ^ (row&7)   [16 B chunks]
//   - read side: b-frag at logical colb = ks*64+quad*16 read from
//     colb ^ ((l16&7)<<4)   [row = 16*(f&3)+l16 -> row&7 = l16&7]
//   Bank check: 4-bank group index = colb' bits 4-6 = {q0^r0, q1^r1, s0^r2}
//   -> 64 lanes uniform over 8 groups (8 each) = min-cycle, same as pad-136.
// X staging stays reg-based (fp32->bf16 convert) into padded Xs[16][136].
// Wave w owns output frags f=3w..3w+2 (which=f>>2, ni=f&3) — r9/r12-proven.
// ---------------------------------------------------------------------------
__global__ __launch_bounds__(256) void qkv_mfma10(
    const float* __restrict__ X, const unsigned short* __restrict__ Wt,
    unsigned short* __restrict__ Q, unsigned short* __restrict__ K,
    unsigned short* __restrict__ Vt)
{
    __shared__ __align__(16) unsigned short Xs[16][136];      //  4.25 KB
    __shared__ __align__(16) unsigned short Ws[3][64][128];   // 48.0 KB linear

    const int tid  = threadIdx.x;
    const int wv   = tid >> 6;
    const int lane = tid & 63;
    const int quad = lane >> 4;
    const int l16  = lane & 15;
    const size_t row0 = (size_t)blockIdx.x * 16;

    floatx4 acc[3];
    #pragma unroll
    for (int j = 0; j < 3; ++j)
        #pragma unroll
        for (int r = 0; r < 4; ++r) acc[j][r] = 0.f;

    const int xrow = tid >> 4;         // 0..15
    const int xc4  = (tid & 15) * 4;   // 0,4,..,60  (covers 64 cols per half)

    // Per-thread W source descriptors (constant across K-steps except k0).
    // flat = tid + 256*j ; which = flat>>10 ; row = (flat>>4)&63 ;
    // src chunk = (flat&15) ^ (row&7)  (16 B chunks = 8 elems).
    // Wave-uniform LDS base for iteration j: Ws + (wv*64 + 256*j)*16 bytes.

    for (int k0 = 0; k0 < Ec; k0 += 128) {
        __syncthreads();
        // Stage X (fp32 -> bf16): 16 rows x 128 cols; 2 x 16 B/thread.
        #pragma unroll
        for (int h = 0; h < 2; ++h) {
            const float4 f = *(const float4*)(X + (row0 + xrow) * Ec + k0 + h * 64 + xc4);
            uint2 p;
            p.x = (unsigned int)f2bf(f.x) | ((unsigned int)f2bf(f.y) << 16);
            p.y = (unsigned int)f2bf(f.z) | ((unsigned int)f2bf(f.w) << 16);
            *(uint2*)&Xs[xrow][h * 64 + xc4] = p;
        }
        // Stage 3 W^T tiles via DMA: 3 x 64 x 128 bf16 = 48 KB;
        // 12 x global_load_lds_dwordx4 per thread, inverse-swizzled source.
        #pragma unroll
        for (int j = 0; j < 12; ++j) {
            const int flat  = tid + 256 * j;        // 0..3071
            const int which = flat >> 10;
            const int r     = (flat >> 4) & 63;
            const int chunk = (flat & 15) ^ (r & 7);
            const unsigned short* src = Wt + which * 65536 + r * 1024 + k0 + chunk * 8;
            char* dst = (char*)&Ws[0][0][0] + (wv * 64 + 256 * j) * 16;
            __builtin_amdgcn_global_load_lds(
                (const __attribute__((address_space(1))) unsigned int*)src,
                (__attribute__((address_space(3))) unsigned int*)dst,
                16, 0, 0);
        }
        __syncthreads();

        #pragma unroll
        for (int ks = 0; ks < 4; ++ks) {
            const short8 a = *(const short8*)&Xs[l16][ks * 32 + quad * 8];
            short8 b[3];
            #pragma unroll
            for (int j = 0; j < 3; ++j) {
                const int f    = 3 * wv + j;
                const int row  = 16 * (f & 3) + l16;
                const int colb = (ks * 64 + quad * 16) ^ ((l16 & 7) << 4);
                b[j] = *(const short8*)((const char*)&Ws[f >> 2][row][0] + colb);
            }
            #pragma unroll
            for (int j = 0; j < 3; ++j)
                acc[j] = __builtin_amdgcn_mfma_f32_16x16x32_bf16(a, b[j], acc[j], 0, 0, 0);
        }
    }

    // Epilogue. C/D: col = lane&15, row = quad*4 + reg (r7-r12-proven).
    #pragma unroll
    for (int j = 0; j < 3; ++j) {
        const int f  = 3 * wv + j;
        const int mf = f >> 2, nf = f & 3;
        if (mf < 2) {
            unsigned short* O = mf == 0 ? Q : K;
            #pragma unroll
            for (int r = 0; r < 4; ++r) {
                float x = acc[j][r];
                if (!(x > -1.0e4f && x < 1.0e4f)) x = 11111.0f;   // diag
                O[(row0 + quad * 4 + r) * Hc + 16 * nf + l16] = f2bf(x);
            }
        } else {
            // V^T: Vt[b][h][t] (r8-proven). 16-row block shares one b.
            const size_t b  = row0 >> 11;
            const int    t0 = (int)(row0 & 2047) + quad * 4;
            unsigned short* VtB = Vt + b * ((size_t)Hc * Tc);
            unsigned int pk[2];
            #pragma unroll
            for (int half = 0; half < 2; ++half) {
                float x0 = acc[j][half * 2 + 0], x1 = acc[j][half * 2 + 1];
                if (!(x0 > -1.0e4f && x0 < 1.0e4f)) x0 = 11111.0f;
                if (!(x1 > -1.0e4f && x1 < 1.0e4f)) x1 = 11111.0f;
                pk[half] = (unsigned int)f2bf(x0) | ((unsigned int)f2bf(x1) << 16);
            }
            uint2 st; st.x = pk[0]; st.y = pk[1];
            *(uint2*)(VtB + (size_t)(16 * nf + l16) * Tc + t0) = st;
        }
    }
}

// ---------------------------------------------------------------------------
// Kernel 2: causal flash attention — r10/r11/r12-proven core + R13 polish
// (R15-verified: -12.8 us total):
//  * balanced dispatch: first 256 blocks qt=127..64 (desc), next 256 qt=0..63
//    (asc) -> per-CU pair sums to constant 129 k-tiles.
//  * lS pre-reduced across l16 via 4x shfl_xor -> epilogue denom 8 LDS reads.
//  * accS epilogue reads as float2.
//  * s_setprio(1) around MFMA clusters.
// ---------------------------------------------------------------------------
__global__ __launch_bounds__(512, 4) void attn_mfma6(
    const unsigned short* __restrict__ Q, const unsigned short* __restrict__ K,
    const unsigned short* __restrict__ Vt, float* __restrict__ Out)
{
    __shared__ __align__(16) unsigned short Pb[8][16][72];   // 18 KB
    __shared__ __align__(16) float accS[8][16][64];          // 32 KB
    __shared__ __align__(16) float lSr[8][16];               // 0.5 KB

    const int tid  = threadIdx.x;
    const int wv   = tid >> 6;            // 0..7
    const int lane = tid & 63;
    const int quad = lane >> 4;
    const int l16  = lane & 15;
    // balanced heavy/light pairing over dispatch-linear id
    const int id   = blockIdx.x + 128 * blockIdx.y;   // 0..511, dispatch order
    const int jj   = id & 255;
    const int qt   = (id < 256) ? (127 - (jj >> 2)) : (jj >> 2);
    const int b    = jj & 3;
    const int qend = qt * 16 + 16;
    const size_t base = (size_t)b * Tc * Hc;
    const unsigned short* VtB = Vt + (size_t)b * Hc * Tc;

    short8 aQ[2];
    #pragma unroll
    for (int ks = 0; ks < 2; ++ks)
        aQ[ks] = *(const short8*)(Q + base +
            (size_t)(qt * 16 + l16) * Hc + ks * 32 + quad * 8);

    floatx4 acc[4];
    float l_st[4];
    #pragma unroll
    for (int nh = 0; nh < 4; ++nh)
        #pragma unroll
        for (int r = 0; r < 4; ++r) acc[nh][r] = 0.f;
    #pragma unroll
    for (int r = 0; r < 4; ++r) l_st[r] = 0.f;

    for (int kb = wv * 64; kb < qend; kb += 512) {
        floatx4 s[4];
        #pragma unroll
        for (int ni = 0; ni < 4; ++ni)
            #pragma unroll
            for (int r = 0; r < 4; ++r) s[ni][r] = 0.f;
        #pragma unroll
        for (int ks = 0; ks < 2; ++ks) {
            short8 bk[4];
            #pragma unroll
            for (int ni = 0; ni < 4; ++ni)
                bk[ni] = *(const short8*)(K + base +
                    (size_t)(kb + 16 * ni + l16) * Hc + ks * 32 + quad * 8);
            __builtin_amdgcn_s_setprio(1);
            #pragma unroll
            for (int ni = 0; ni < 4; ++ni)
                s[ni] = __builtin_amdgcn_mfma_f32_16x16x32_bf16(aQ[ks], bk[ni], s[ni], 0, 0, 0);
            __builtin_amdgcn_s_setprio(0);
        }

        #pragma unroll
        for (int r = 0; r < 4; ++r) {
            const int qrow = qt * 16 + quad * 4 + r;
            #pragma unroll
            for (int ni = 0; ni < 4; ++ni) {
                const int kcol = kb + 16 * ni + l16;
                const float p = (kcol > qrow) ? 0.f : __expf(s[ni][r] * SCALE);
                s[ni][r] = p;
                l_st[r] += p;
            }
        }
        #pragma unroll
        for (int ni = 0; ni < 4; ++ni)
            #pragma unroll
            for (int r = 0; r < 4; ++r)
                Pb[wv][quad * 4 + r][16 * ni + l16] = f2bf(s[ni][r]);

        #pragma unroll
        for (int ks = 0; ks < 2; ++ks) {
            const short8 aP = *(const short8*)&Pb[wv][l16][ks * 32 + quad * 8];
            short8 bv[4];
            #pragma unroll
            for (int nh = 0; nh < 4; ++nh)
                bv[nh] = *(const short8*)(VtB +
                    (size_t)(16 * nh + l16) * Tc + kb + ks * 32 + quad * 8);
            __builtin_amdgcn_s_setprio(1);
            #pragma unroll
            for (int nh = 0; nh < 4; ++nh)
                acc[nh] = __builtin_amdgcn_mfma_f32_16x16x32_bf16(aP, bv[nh], acc[nh], 0, 0, 0);
            __builtin_amdgcn_s_setprio(0);
        }
    }

    #pragma unroll
    for (int nh = 0; nh < 4; ++nh)
        #pragma unroll
        for (int r = 0; r < 4; ++r)
            accS[wv][quad * 4 + r][16 * nh + l16] = acc[nh][r];
    // reduce l_st across the 16 lanes of each quad (xor masks 1,2,4,8 stay
    // within the 16-lane group), then one scalar per (wave, q-row)
    #pragma unroll
    for (int r = 0; r < 4; ++r) {
        float v = l_st[r];
        v += __shfl_xor(v, 1);
        v += __shfl_xor(v, 2);
        v += __shfl_xor(v, 4);
        v += __shfl_xor(v, 8);
        l_st[r] = v;
    }
    if (l16 == 0)
        #pragma unroll
        for (int r = 0; r < 4; ++r)
            lSr[wv][quad * 4 + r] = l_st[r];
    __syncthreads();

    {
        const int q  = tid >> 5;              // 0..15
        const int h0 = (tid & 31) * 2;        // 0..62
        float denom = 0.f;
        #pragma unroll
        for (int w = 0; w < 8; ++w)
            denom += lSr[w][q];
        const float inv = 1.f / denom;
        float o0 = 0.f, o1 = 0.f;
        #pragma unroll
        for (int w = 0; w < 8; ++w) {
            const float2 v = *(const float2*)&accS[w][q][h0];
            o0 += v.x; o1 += v.y;
        }
        o0 *= inv; o1 *= inv;
        if (!(o0 > -1.0e5f && o0 < 1.0e5f)) o0 = 555.0f;   // diag
        if (!(o1 > -1.0e5f && o1 < 1.0e5f)) o1 = 555.0f;
        float2 st; st.x = o0; st.y = o1;
        *(float2*)(Out + base + (size_t)(qt * 16 + q) * Hc + h0) = st;
    }
}

extern "C" void kernel_launch(void* const* d_in, const int* in_sizes, int n_in,
                              void* d_out, int out_size, void* d_ws, size_t ws_size,
                              hipStream_t stream)
{
    const float* X  = (const float*)d_in[0];
    const float* Wq = (const float*)d_in[1];
    const float* Wk = (const float*)d_in[2];
    const float* Wv = (const float*)d_in[3];

    const size_t N = (size_t)Bc * Tc * Hc;          // 524,288
    unsigned short* Wt  = (unsigned short*)d_ws;    // 384 KB bf16 W^T x3
    unsigned short* Qws = Wt + 3 * (size_t)Ec * Hc; // 1 MB
    unsigned short* Kws = Qws + N;                  // 1 MB
    unsigned short* Vtw = Kws + N;                  // 1 MB (V^T [b][h][t])

    prep_w<<<dim3(64, 3), dim3(256), 0, stream>>>(Wq, Wk, Wv, Wt);
    qkv_mfma10<<<dim3(512), dim3(256), 0, stream>>>(X, Wt, Qws, Kws, Vtw);
    attn_mfma6<<<dim3(128, 4), dim3(512), 0, stream>>>(
        Qws, Kws, Vtw, (float*)d_out);
}

// Round 5
// 106.150 us; speedup vs baseline: 1.0184x; 1.0184x over previous
//
#include <hip/hip_runtime.h>
#include <hip/hip_bf16.h>

// (B,T,E,H) = (4, 2048, 1024, 64); scale = E^-0.5 = 1/32.
// Ground truth: inputs fp32, output fp32. ws >= 268 MB.
// dur_us model: ~86 us fixed poison fills (2 x ~43 us, immovable) + ~21 us
// controllable (prep_w ~3, qkv ~10, attn ~5-6, gaps).
// R17: qkv -> 32-row/512-thr blocks + DOUBLE-BUFFERED LDS, raw s_barrier,
// single vmcnt/lgkm drain per K-step issued AFTER next-tile loads (T3
// minimum-2-phase). This is R13's W-amortization (halves W staging per
// output) WITHOUT R13's failure mode: R13 kept __syncthreads x2/step, which
// drains vmcnt(0) both times -> 1-block/CU stalled (MfmaUtil 2.5%). Here the
// next tile's loads (6 W-DMA + 2 X-loads) fly across the whole compute phase.
// Proven pieces reused: 32-row frag map (R14 ran correct), W DMA + XOR
// involution (R16 correct, absmax identical), epilogue (r8-r12).
// attn_mfma6 unchanged (R15-verified -12.8 us).
constexpr int Bc = 4;
constexpr int Tc = 2048;
constexpr int Ec = 1024;
constexpr int Hc = 64;
constexpr float SCALE = 0.03125f;

typedef short  short8  __attribute__((ext_vector_type(8)));
typedef float  floatx4 __attribute__((ext_vector_type(4)));

__device__ __forceinline__ unsigned short f2bf(float f) {  // RNE
    union { float f; unsigned int i; } x;
    x.f = f;
    unsigned int r = x.i + 0x7fffu + ((x.i >> 16) & 1u);
    return (unsigned short)(r >> 16);
}

// ---------------------------------------------------------------------------
// Kernel 0: W fp32 [E][H] -> Wt bf16 [H][E], x3 (r7-r12-proven). ~3 us.
// ---------------------------------------------------------------------------
__global__ __launch_bounds__(256) void prep_w(
    const float* __restrict__ Wq, const float* __restrict__ Wk,
    const float* __restrict__ Wv, unsigned short* __restrict__ Wt)
{
    const float* W = blockIdx.y == 0 ? Wq : (blockIdx.y == 1 ? Wk : Wv);
    unsigned short* D = Wt + (size_t)blockIdx.y * (Ec * Hc);
    const int i0 = blockIdx.x * 1024 + threadIdx.x * 4;
    const float4 f = *(const float4*)(W + i0);
    const float v[4] = {f.x, f.y, f.z, f.w};
    #pragma unroll
    for (int j = 0; j < 4; ++j) {
        const int i = i0 + j;            // i = e*64 + h
        D[(i & 63) * Ec + (i >> 6)] = f2bf(v[j]);
    }
}

// ---------------------------------------------------------------------------
// Kernel 1: FUSED QKV projection, MFMA 16x16x32 bf16, K=128 steps, 2-phase
// double-buffer. Grid 256 x 512 thr (1 block/CU, 8 waves = 2/SIMD).
// LDS: Xs[2][32][136] (17 KB, pad-136 proven bank math) +
//      Ws[2][3][64][128] (96 KB, linear for DMA) = 113 KB.
// Per K-step: issue next tile (2 float4 X-loads + 6 W-DMA) -> compute cur
// (16 ds_read_b128 + 12 MFMA/wave) -> convert+ds_write X(next) ->
// s_waitcnt vmcnt(0) lgkmcnt(0) -> s_barrier. ONE barrier/step; loads get
// the whole compute phase to fly.
// W involution (R16-proven): store-side source chunk ^= (row&7); read-side
// colb ^= ((l16&7)<<4). Uniform 8 lanes per 4-bank group.
// Buffer safety: DMA into buf B issues only after the barrier that follows
// all reads of buf B (reads happened in the prior iteration).
// Wave wv: rowh=wv>>2 (16-row half), wq=wv&3; frags f=3*wq..3*wq+2
// (which=f>>2, nf=f&3) — R14-run-proven 32-row map.
// ---------------------------------------------------------------------------
__global__ __launch_bounds__(512, 2) void qkv_mfma11(
    const float* __restrict__ X, const unsigned short* __restrict__ Wt,
    unsigned short* __restrict__ Q, unsigned short* __restrict__ K,
    unsigned short* __restrict__ Vt)
{
    __shared__ __align__(16) unsigned short Xs[2][32][136];      // 17.0 KB
    __shared__ __align__(16) unsigned short Ws[2][3][64][128];   // 96.0 KB

    const int tid  = threadIdx.x;
    const int wv   = tid >> 6;          // 0..7
    const int lane = tid & 63;
    const int quad = lane >> 4;
    const int l16  = lane & 15;
    const int rowh = wv >> 2;           // 0..1
    const int wq   = wv & 3;            // 0..3
    const size_t row0 = (size_t)blockIdx.x * 32;

    floatx4 acc[3];
    #pragma unroll
    for (int j = 0; j < 3; ++j)
        #pragma unroll
        for (int r = 0; r < 4; ++r) acc[j][r] = 0.f;

    const int xrow = tid >> 4;         // 0..31
    const int xc4  = (tid & 15) * 4;   // 0,4,..,60

    // ---- prologue: stage buffer 0 (k0 = 0) ----
    {
        float4 xr[2];
        #pragma unroll
        for (int h = 0; h < 2; ++h)
            xr[h] = *(const float4*)(X + (row0 + xrow) * Ec + h * 64 + xc4);
        #pragma unroll
        for (int j = 0; j < 6; ++j) {
            const int flat  = tid + 512 * j;        // 0..3071
            const int which = flat >> 10;
            const int r     = (flat >> 4) & 63;
            const int chunk = (flat & 15) ^ (r & 7);
            const unsigned short* src = Wt + which * 65536 + r * 1024 + chunk * 8;
            char* dst = (char*)&Ws[0][0][0][0] + (wv * 64 + 512 * j) * 16;
            __builtin_amdgcn_global_load_lds(
                (const __attribute__((address_space(1))) unsigned int*)src,
                (__attribute__((address_space(3))) unsigned int*)dst,
                16, 0, 0);
        }
        #pragma unroll
        for (int h = 0; h < 2; ++h) {
            uint2 p;
            p.x = (unsigned int)f2bf(xr[h].x) | ((unsigned int)f2bf(xr[h].y) << 16);
            p.y = (unsigned int)f2bf(xr[h].z) | ((unsigned int)f2bf(xr[h].w) << 16);
            *(uint2*)&Xs[0][xrow][h * 64 + xc4] = p;
        }
        asm volatile("s_waitcnt vmcnt(0) lgkmcnt(0)" ::: "memory");
        __builtin_amdgcn_s_barrier();
    }

    for (int t = 0; t < 8; ++t) {
        const int cur = t & 1;
        float4 xr[2];
        // ---- issue next tile's loads (fly across the compute phase) ----
        if (t < 7) {
            const int k1 = (t + 1) * 128;
            #pragma unroll
            for (int h = 0; h < 2; ++h)
                xr[h] = *(const float4*)(X + (row0 + xrow) * Ec + k1 + h * 64 + xc4);
            #pragma unroll
            for (int j = 0; j < 6; ++j) {
                const int flat  = tid + 512 * j;
                const int which = flat >> 10;
                const int r     = (flat >> 4) & 63;
                const int chunk = (flat & 15) ^ (r & 7);
                const unsigned short* src = Wt + which * 65536 + r * 1024 + k1 + chunk * 8;
                char* dst = (char*)&Ws[cur ^ 1][0][0][0] + (wv * 64 + 512 * j) * 16;
                __builtin_amdgcn_global_load_lds(
                    (const __attribute__((address_space(1))) unsigned int*)src,
                    (__attribute__((address_space(3))) unsigned int*)dst,
                    16, 0, 0);
            }
        }
        __builtin_amdgcn_sched_barrier(0);   // pin load-issue above compute
        // ---- compute on buffer cur ----
        #pragma unroll
        for (int ks = 0; ks < 4; ++ks) {
            const short8 a = *(const short8*)&Xs[cur][rowh * 16 + l16][ks * 32 + quad * 8];
            short8 b[3];
            #pragma unroll
            for (int j = 0; j < 3; ++j) {
                const int f    = 3 * wq + j;
                const int row  = 16 * (f & 3) + l16;
                const int colb = (ks * 64 + quad * 16) ^ ((l16 & 7) << 4);
                b[j] = *(const short8*)((const char*)&Ws[cur][f >> 2][row][0] + colb);
            }
            #pragma unroll
            for (int j = 0; j < 3; ++j)
                acc[j] = __builtin_amdgcn_mfma_f32_16x16x32_bf16(a, b[j], acc[j], 0, 0, 0);
        }
        if (t < 7) {
            __builtin_amdgcn_sched_barrier(0);   // keep X-converts after compute
            // ---- convert + write X(next); X loads had the compute to land ----
            #pragma unroll
            for (int h = 0; h < 2; ++h) {
                uint2 p;
                p.x = (unsigned int)f2bf(xr[h].x) | ((unsigned int)f2bf(xr[h].y) << 16);
                p.y = (unsigned int)f2bf(xr[h].z) | ((unsigned int)f2bf(xr[h].w) << 16);
                *(uint2*)&Xs[cur ^ 1][xrow][h * 64 + xc4] = p;
            }
            asm volatile("s_waitcnt vmcnt(0) lgkmcnt(0)" ::: "memory");
            __builtin_amdgcn_s_barrier();
        }
    }

    // Epilogue. C/D: col = lane&15, row = quad*4 + reg (r7-r12-proven).
    const size_t rbase = row0 + rowh * 16;
    #pragma unroll
    for (int j = 0; j < 3; ++j) {
        const int f  = 3 * wq + j;
        const int mf = f >> 2, nf = f & 3;
        if (mf < 2) {
            unsigned short* O = mf == 0 ? Q : K;
            #pragma unroll
            for (int r = 0; r < 4; ++r) {
                float x = acc[j][r];
                if (!(x > -1.0e4f && x < 1.0e4f)) x = 11111.0f;   // diag
                O[(rbase + quad * 4 + r) * Hc + 16 * nf + l16] = f2bf(x);
            }
        } else {
            // V^T: Vt[b][h][t] (r8-proven). 16-row half shares one b.
            const size_t b  = rbase >> 11;
            const int    t0 = (int)(rbase & 2047) + quad * 4;
            unsigned short* VtB = Vt + b * ((size_t)Hc * Tc);
            unsigned int pk[2];
            #pragma unroll
            for (int half = 0; half < 2; ++half) {
                float x0 = acc[j][half * 2 + 0], x1 = acc[j][half * 2 + 1];
                if (!(x0 > -1.0e4f && x0 < 1.0e4f)) x0 = 11111.0f;
                if (!(x1 > -1.0e4f && x1 < 1.0e4f)) x1 = 11111.0f;
                pk[half] = (unsigned int)f2bf(x0) | ((unsigned int)f2bf(x1) << 16);
            }
            uint2 st; st.x = pk[0]; st.y = pk[1];
            *(uint2*)(VtB + (size_t)(16 * nf + l16) * Tc + t0) = st;
        }
    }
}

// ---------------------------------------------------------------------------
// Kernel 2: causal flash attention — r10/r11/r12-proven core + R13 polish
// (R15-verified: -12.8 us total):
//  * balanced dispatch: first 256 blocks qt=127..64 (desc), next 256 qt=0..63
//    (asc) -> per-CU pair sums to constant 129 k-tiles.
//  * lS pre-reduced across l16 via 4x shfl_xor -> epilogue denom 8 LDS reads.
//  * accS epilogue reads as float2.
//  * s_setprio(1) around MFMA clusters.
// ---------------------------------------------------------------------------
__global__ __launch_bounds__(512, 4) void attn_mfma6(
    const unsigned short* __restrict__ Q, const unsigned short* __restrict__ K,
    const unsigned short* __restrict__ Vt, float* __restrict__ Out)
{
    __shared__ __align__(16) unsigned short Pb[8][16][72];   // 18 KB
    __shared__ __align__(16) float accS[8][16][64];          // 32 KB
    __shared__ __align__(16) float lSr[8][16];               // 0.5 KB

    const int tid  = threadIdx.x;
    const int wv   = tid >> 6;            // 0..7
    const int lane = tid & 63;
    const int quad = lane >> 4;
    const int l16  = lane & 15;
    // balanced heavy/light pairing over dispatch-linear id
    const int id   = blockIdx.x + 128 * blockIdx.y;   // 0..511, dispatch order
    const int jj   = id & 255;
    const int qt   = (id < 256) ? (127 - (jj >> 2)) : (jj >> 2);
    const int b    = jj & 3;
    const int qend = qt * 16 + 16;
    const size_t base = (size_t)b * Tc * Hc;
    const unsigned short* VtB = Vt + (size_t)b * Hc * Tc;

    short8 aQ[2];
    #pragma unroll
    for (int ks = 0; ks < 2; ++ks)
        aQ[ks] = *(const short8*)(Q + base +
            (size_t)(qt * 16 + l16) * Hc + ks * 32 + quad * 8);

    floatx4 acc[4];
    float l_st[4];
    #pragma unroll
    for (int nh = 0; nh < 4; ++nh)
        #pragma unroll
        for (int r = 0; r < 4; ++r) acc[nh][r] = 0.f;
    #pragma unroll
    for (int r = 0; r < 4; ++r) l_st[r] = 0.f;

    for (int kb = wv * 64; kb < qend; kb += 512) {
        floatx4 s[4];
        #pragma unroll
        for (int ni = 0; ni < 4; ++ni)
            #pragma unroll
            for (int r = 0; r < 4; ++r) s[ni][r] = 0.f;
        #pragma unroll
        for (int ks = 0; ks < 2; ++ks) {
            short8 bk[4];
            #pragma unroll
            for (int ni = 0; ni < 4; ++ni)
                bk[ni] = *(const short8*)(K + base +
                    (size_t)(kb + 16 * ni + l16) * Hc + ks * 32 + quad * 8);
            __builtin_amdgcn_s_setprio(1);
            #pragma unroll
            for (int ni = 0; ni < 4; ++ni)
                s[ni] = __builtin_amdgcn_mfma_f32_16x16x32_bf16(aQ[ks], bk[ni], s[ni], 0, 0, 0);
            __builtin_amdgcn_s_setprio(0);
        }

        #pragma unroll
        for (int r = 0; r < 4; ++r) {
            const int qrow = qt * 16 + quad * 4 + r;
            #pragma unroll
            for (int ni = 0; ni < 4; ++ni) {
                const int kcol = kb + 16 * ni + l16;
                const float p = (kcol > qrow) ? 0.f : __expf(s[ni][r] * SCALE);
                s[ni][r] = p;
                l_st[r] += p;
            }
        }
        #pragma unroll
        for (int ni = 0; ni < 4; ++ni)
            #pragma unroll
            for (int r = 0; r < 4; ++r)
                Pb[wv][quad * 4 + r][16 * ni + l16] = f2bf(s[ni][r]);

        #pragma unroll
        for (int ks = 0; ks < 2; ++ks) {
            const short8 aP = *(const short8*)&Pb[wv][l16][ks * 32 + quad * 8];
            short8 bv[4];
            #pragma unroll
            for (int nh = 0; nh < 4; ++nh)
                bv[nh] = *(const short8*)(VtB +
                    (size_t)(16 * nh + l16) * Tc + kb + ks * 32 + quad * 8);
            __builtin_amdgcn_s_setprio(1);
            #pragma unroll
            for (int nh = 0; nh < 4; ++nh)
                acc[nh] = __builtin_amdgcn_mfma_f32_16x16x32_bf16(aP, bv[nh], acc[nh], 0, 0, 0);
            __builtin_amdgcn_s_setprio(0);
        }
    }

    #pragma unroll
    for (int nh = 0; nh < 4; ++nh)
        #pragma unroll
        for (int r = 0; r < 4; ++r)
            accS[wv][quad * 4 + r][16 * nh + l16] = acc[nh][r];
    // reduce l_st across the 16 lanes of each quad (xor masks 1,2,4,8 stay
    // within the 16-lane group), then one scalar per (wave, q-row)
    #pragma unroll
    for (int r = 0; r < 4; ++r) {
        float v = l_st[r];
        v += __shfl_xor(v, 1);
        v += __shfl_xor(v, 2);
        v += __shfl_xor(v, 4);
        v += __shfl_xor(v, 8);
        l_st[r] = v;
    }
    if (l16 == 0)
        #pragma unroll
        for (int r = 0; r < 4; ++r)
            lSr[wv][quad * 4 + r] = l_st[r];
    __syncthreads();

    {
        const int q  = tid >> 5;              // 0..15
        const int h0 = (tid & 31) * 2;        // 0..62
        float denom = 0.f;
        #pragma unroll
        for (int w = 0; w < 8; ++w)
            denom += lSr[w][q];
        const float inv = 1.f / denom;
        float o0 = 0.f, o1 = 0.f;
        #pragma unroll
        for (int w = 0; w < 8; ++w) {
            const float2 v = *(const float2*)&accS[w][q][h0];
            o0 += v.x; o1 += v.y;
        }
        o0 *= inv; o1 *= inv;
        if (!(o0 > -1.0e5f && o0 < 1.0e5f)) o0 = 555.0f;   // diag
        if (!(o1 > -1.0e5f && o1 < 1.0e5f)) o1 = 555.0f;
        float2 st; st.x = o0; st.y = o1;
        *(float2*)(Out + base + (size_t)(qt * 16 + q) * Hc + h0) = st;
    }
}

extern "C" void kernel_launch(void* const* d_in, const int* in_sizes, int n_in,
                              void* d_out, int out_size, void* d_ws, size_t ws_size,
                              hipStream_t stream)
{
    const float* X  = (const float*)d_in[0];
    const float* Wq = (const float*)d_in[1];
    const float* Wk = (const float*)d_in[2];
    const float* Wv = (const float*)d_in[3];

    const size_t N = (size_t)Bc * Tc * Hc;          // 524,288
    unsigned short* Wt  = (unsigned short*)d_ws;    // 384 KB bf16 W^T x3
    unsigned short* Qws = Wt + 3 * (size_t)Ec * Hc; // 1 MB
    unsigned short* Kws = Qws + N;                  // 1 MB
    unsigned short* Vtw = Kws + N;                  // 1 MB (V^T [b][h][t])

    prep_w<<<dim3(64, 3), dim3(256), 0, stream>>>(Wq, Wk, Wv, Wt);
    qkv_mfma11<<<dim3(256), dim3(512), 0, stream>>>(X, Wt, Qws, Kws, Vtw);
    attn_mfma6<<<dim3(128, 4), dim3(512), 0, stream>>>(
        Qws, Kws, Vtw, (float*)d_out);
}